// Round 16
// baseline (57.109 us; speedup 1.0000x reference)
//
#include <hip/hip_runtime.h>

#define K_OFF 27
#define CIN   2
#define COUT  16
#define BLK   256
#define WPB   4
#define IPW   (64 * K_OFF)      // 1728 ints per tile
#define NB    8

typedef __attribute__((address_space(3))) unsigned int lds_u32;
typedef __attribute__((address_space(1))) const unsigned int g_u32;

// ---- prologue: pack fp32 feats [N][2] -> bf16x2 u32 [N] (RTNE) ----
__global__ __launch_bounds__(256) void pack_feats_kernel(
    const float2* __restrict__ feats2, unsigned* __restrict__ pkf, int n)
{
    const int i = blockIdx.x * 256 + threadIdx.x;
    if (i < n) {
        const float2 f = feats2[i];
        unsigned bx = __float_as_uint(f.x);
        unsigned by = __float_as_uint(f.y);
        bx = (bx + 0x7FFFu + ((bx >> 16) & 1u)) >> 16;
        by = (by + 0x7FFFu + ((by >> 16) & 1u)) >> 16;
        pkf[i] = bx | (by << 16);
    }
}

__device__ __forceinline__ void stage_tile(const int* __restrict__ nbr,
                                           int tile, int* dst, int lane) {
    const int* src = nbr + (size_t)tile * IPW;
    #pragma unroll
    for (int j = 0; j < 6; ++j)
        __builtin_amdgcn_global_load_lds((g_u32*)(src + j * 256 + lane * 4),
                                         (lds_u32*)(dst + j * 256), 16, 0, 0);
    if (lane < 48)
        __builtin_amdgcn_global_load_lds((g_u32*)(src + 6 * 256 + lane * 4),
                                         (lds_u32*)(dst + 6 * 256), 16, 0, 0);
}   // 7 vmem ops when executed

// scan BUF, capture kk[16] + ix[8] (batch2) + nv, issue batch1 gathers -> GB
#define SCAN_CAP_ISSUE(BUF, GB, KK, IX, NV, MX)                               \
    {                                                                         \
        const int* rowp_ = (BUF) + lane * K_OFF;                              \
        unsigned b_ = 0;                                                      \
        _Pragma("unroll")                                                     \
        for (int k2 = 0; k2 < K_OFF; ++k2)                                    \
            b_ |= (rowp_[k2] >= 0) ? (1u << k2) : 0u;                         \
        NV = __popc(b_);                                                      \
        int m_ = NV;                                                          \
        _Pragma("unroll")                                                     \
        for (int o_ = 32; o_; o_ >>= 1) m_ = max(m_, __shfl_xor(m_, o_, 64)); \
        MX = m_;                                                              \
        _Pragma("unroll")                                                     \
        for (int j = 0; j < 2 * NB; ++j) {                                    \
            KK[j] = (b_ != 0) ? (int)__builtin_ctz(b_) : 0;                   \
            b_ &= b_ - 1;                                                     \
        }                                                                     \
        _Pragma("unroll")                                                     \
        for (int j = 0; j < NB; ++j) {    /* batch2 idx -> regs */            \
            const int ii_ = rowp_[KK[NB + j]];                                \
            IX[j] = (NB + j < NV && ii_ > 0) ? ii_ : 0;                       \
        }                                                                     \
        _Pragma("unroll")                                                     \
        for (int j = 0; j < NB; ++j) {    /* batch1 gathers (per-lane src) */ \
            const int iv_ = rowp_[KK[j]];                                     \
            const int sf_ = (j < NV && iv_ > 0) ? iv_ : 0;                    \
            __builtin_amdgcn_global_load_lds((g_u32*)(pkf + sf_),             \
                                             (lds_u32*)((GB) + j * 64), 4, 0, 0); \
        }                                                                     \
    }

#define FMA_LDS(GB, KK, NV, JOFF)                                             \
    _Pragma("unroll")                                                         \
    for (int j = 0; j < NB; ++j) {                                            \
        const unsigned u_ = (unsigned)(GB)[j * 64 + lane];                    \
        const float fm_ = ((JOFF) + j < (NV)) ? 1.0f : 0.0f;                  \
        const float fx = __uint_as_float(u_ << 16) * fm_;                     \
        const float fy = __uint_as_float(u_ & 0xFFFF0000u) * fm_;             \
        const int k2 = KK[(JOFF) + j];                                        \
        _Pragma("unroll")                                                     \
        for (int q = 0; q < 4; ++q) {                                         \
            const float4 wa = s_w[q * K_OFF + k2];                            \
            const float4 wb = s_w[(q + 4) * K_OFF + k2];                      \
            acc[4*q+0] = fmaf(fy, wb.x, fmaf(fx, wa.x, acc[4*q+0]));          \
            acc[4*q+1] = fmaf(fy, wb.y, fmaf(fx, wa.y, acc[4*q+1]));          \
            acc[4*q+2] = fmaf(fy, wb.z, fmaf(fx, wa.z, acc[4*q+2]));          \
            acc[4*q+3] = fmaf(fy, wb.w, fmaf(fx, wa.w, acc[4*q+3]));          \
        }                                                                     \
    }

__global__ __launch_bounds__(BLK, 2) void spconv_pipe_kernel(
    const unsigned* __restrict__ pkf,  // [N] bf16x2, 4 MB
    const float*    __restrict__ w,    // [27][2][16]
    const int*      __restrict__ nbr,  // [N][27]
    float*          __restrict__ out,  // [N][16]
    int n_tiles)                       // all tiles FULL (64 pts)
{
    __shared__ int    s_idx[WPB * 2 * IPW];       // 55296 B
    __shared__ int    s_g  [WPB * 2 * NB * 64];   // 16384 B
    __shared__ float4 s_w  [8 * K_OFF];           // 3456 B  (total 75136 -> 2 blk/CU)

    const int t    = threadIdx.x;
    const int lane = t & 63;
    const int wv   = t >> 6;

    if (t < 8 * K_OFF) {
        const int k = t >> 3, q = t & 7;
        s_w[q * K_OFF + k] = reinterpret_cast<const float4*>(w)[t];
    }
    __syncthreads();

    const int wstride = gridDim.x * WPB;
    int tile = blockIdx.x * WPB + wv;
    if (tile >= n_tiles) return;

    int* const bufA = s_idx + wv * (2 * IPW);
    int* const bufB = bufA + IPW;
    int* const gbA  = s_g + wv * (2 * NB * 64);
    int* const gbB  = gbA + NB * 64;

    int kk1[2 * NB], ix1[NB], nv1, mx1;
    int kk2[2 * NB], ix2[NB], nv2, mx2;

    // ---- prologue: S(t0); drain; scan(t0)+G(t0); S(t1) ----
    stage_tile(nbr, tile, bufA, lane);
    asm volatile("s_waitcnt vmcnt(0)" ::: "memory");
    __builtin_amdgcn_sched_barrier(0);
    SCAN_CAP_ISSUE(bufA, gbA, kk1, ix1, nv1, mx1)
    if (tile + wstride < n_tiles) stage_tile(nbr, tile + wstride, bufB, lane);

    int  cur   = 0;
    bool first = true;

    while (true) {
        const int  nxt  = tile + wstride;
        const bool has1 = (nxt < n_tiles);
        const int  n2   = tile + 2 * wstride;
        const bool has2 = (n2 < n_tiles);

        int* const bufC = cur ? bufB : bufA;
        int* const bufN = cur ? bufA : bufB;
        int* const gbC  = cur ? gbB  : gbA;
        int* const gbN  = cur ? gbA  : gbB;

        // single wait: queue is [S7(T+1), G8(T), st4(T-1)] -> vmcnt(4)
        // retires S+G exactly, leaves stores. First iter has no stores.
        if (first) asm volatile("s_waitcnt vmcnt(0)" ::: "memory");
        else       asm volatile("s_waitcnt vmcnt(4)" ::: "memory");
        first = false;
        __builtin_amdgcn_sched_barrier(0);

        // earliest stage: S(T+2) -> bufC (free: scan(T) done, batch2 uses regs)
        const bool early_stage = has2 && (mx1 <= 2 * NB);
        if (early_stage) stage_tile(nbr, n2, bufC, lane);

        if (has1) SCAN_CAP_ISSUE(bufN, gbN, kk2, ix2, nv2, mx2)

        float acc[COUT];
        #pragma unroll
        for (int d = 0; d < COUT; ++d) acc[d] = 0.f;

        FMA_LDS(gbC, kk1, nv1, 0)

        if (mx1 > NB) {   // batch 2 (rare): idx from regs, reuse gbC
            asm volatile("s_waitcnt lgkmcnt(0)" ::: "memory");
            __builtin_amdgcn_sched_barrier(0);
            #pragma unroll
            for (int j = 0; j < NB; ++j)
                __builtin_amdgcn_global_load_lds((g_u32*)(pkf + ix1[j]),
                                                 (lds_u32*)(gbC + j * 64), 4, 0, 0);
            asm volatile("s_waitcnt vmcnt(0)" ::: "memory");
            __builtin_amdgcn_sched_barrier(0);
            FMA_LDS(gbC, kk1, nv1, NB)

            if (mx1 > 2 * NB) {   // batches 3+ (astronomically rare), bufC intact
                const int* rowp_ = bufC + lane * K_OFF;
                unsigned b_ = 0;
                #pragma unroll
                for (int k2 = 0; k2 < K_OFF; ++k2)
                    b_ |= (rowp_[k2] >= 0) ? (1u << k2) : 0u;
                #pragma unroll
                for (int j = 0; j < 2 * NB; ++j) b_ &= b_ - 1;
                int rem = mx1 - 2 * NB;
                while (rem > 0) {
                    int kkx[NB]; float fmx[NB];
                    #pragma unroll
                    for (int j = 0; j < NB; ++j) {
                        const bool a_ = (b_ != 0);
                        kkx[j] = a_ ? (int)__builtin_ctz(b_) : 0;
                        fmx[j] = a_ ? 1.0f : 0.0f;
                        b_ &= b_ - 1;
                    }
                    asm volatile("s_waitcnt lgkmcnt(0)" ::: "memory");
                    __builtin_amdgcn_sched_barrier(0);
                    #pragma unroll
                    for (int j = 0; j < NB; ++j) {
                        const int iv_ = rowp_[kkx[j]];
                        const int sf_ = (fmx[j] > 0.f && iv_ > 0) ? iv_ : 0;
                        __builtin_amdgcn_global_load_lds((g_u32*)(pkf + sf_),
                                                         (lds_u32*)(gbC + j * 64), 4, 0, 0);
                    }
                    asm volatile("s_waitcnt vmcnt(0)" ::: "memory");
                    __builtin_amdgcn_sched_barrier(0);
                    #pragma unroll
                    for (int j = 0; j < NB; ++j) {
                        const unsigned u_ = (unsigned)gbC[j * 64 + lane];
                        const float fx = __uint_as_float(u_ << 16) * fmx[j];
                        const float fy = __uint_as_float(u_ & 0xFFFF0000u) * fmx[j];
                        const int k2 = kkx[j];
                        #pragma unroll
                        for (int q = 0; q < 4; ++q) {
                            const float4 wa = s_w[q * K_OFF + k2];
                            const float4 wb = s_w[(q + 4) * K_OFF + k2];
                            acc[4*q+0] = fmaf(fy, wb.x, fmaf(fx, wa.x, acc[4*q+0]));
                            acc[4*q+1] = fmaf(fy, wb.y, fmaf(fx, wa.y, acc[4*q+1]));
                            acc[4*q+2] = fmaf(fy, wb.z, fmaf(fx, wa.z, acc[4*q+2]));
                            acc[4*q+3] = fmaf(fy, wb.w, fmaf(fx, wa.w, acc[4*q+3]));
                        }
                    }
                    rem -= NB;
                }
                if (has2) stage_tile(nbr, n2, bufC, lane);   // late stage
            }
        }

        {   // coalesced stores (4 vmem ops)
            const int p = tile * 64 + lane;
            float4* o = reinterpret_cast<float4*>(out + (size_t)p * COUT);
            o[0] = make_float4(acc[0],  acc[1],  acc[2],  acc[3]);
            o[1] = make_float4(acc[4],  acc[5],  acc[6],  acc[7]);
            o[2] = make_float4(acc[8],  acc[9],  acc[10], acc[11]);
            o[3] = make_float4(acc[12], acc[13], acc[14], acc[15]);
        }

        if (!has1) break;

        #pragma unroll
        for (int j = 0; j < 2 * NB; ++j) kk1[j] = kk2[j];
        #pragma unroll
        for (int j = 0; j < NB; ++j) ix1[j] = ix2[j];
        nv1 = nv2; mx1 = mx2;

        tile = nxt;
        cur ^= 1;
    }
}

// generic remainder (n_pts % 64) — not launched for n = 1M
__global__ __launch_bounds__(64) void spconv_tail_kernel(
    const unsigned* __restrict__ pkf, const float* __restrict__ w,
    const int* __restrict__ nbr, float* __restrict__ out, int n_pts, int p0)
{
    const int p = p0 + threadIdx.x;
    if (p >= n_pts) return;
    float acc[COUT];
    #pragma unroll
    for (int d = 0; d < COUT; ++d) acc[d] = 0.f;
    for (int k = 0; k < K_OFF; ++k) {
        const int idx = nbr[(size_t)p * K_OFF + k];
        if (idx >= 0) {
            const unsigned u = pkf[idx];
            const float fx = __uint_as_float(u << 16);
            const float fy = __uint_as_float(u & 0xFFFF0000u);
            #pragma unroll
            for (int d = 0; d < COUT; ++d)
                acc[d] = fmaf(fy, w[k * 32 + 16 + d], fmaf(fx, w[k * 32 + d], acc[d]));
        }
    }
    float4* o = reinterpret_cast<float4*>(out + (size_t)p * COUT);
    o[0] = make_float4(acc[0],  acc[1],  acc[2],  acc[3]);
    o[1] = make_float4(acc[4],  acc[5],  acc[6],  acc[7]);
    o[2] = make_float4(acc[8],  acc[9],  acc[10], acc[11]);
    o[3] = make_float4(acc[12], acc[13], acc[14], acc[15]);
}

extern "C" void kernel_launch(void* const* d_in, const int* in_sizes, int n_in,
                              void* d_out, int out_size, void* d_ws, size_t ws_size,
                              hipStream_t stream) {
    const float* feats = (const float*)d_in[0];
    const float* w     = (const float*)d_in[1];
    const int*   nbr   = (const int*)d_in[2];
    float*       out   = (float*)d_out;
    unsigned*    pkf   = (unsigned*)d_ws;

    const int n_pts  = in_sizes[0] / CIN;
    const int n_full = n_pts / 64;
    const int rem    = n_pts % 64;

    pack_feats_kernel<<<(n_pts + 255) / 256, 256, 0, stream>>>(
        reinterpret_cast<const float2*>(feats), pkf, n_pts);

    if (n_full > 0) {
        int grid = (n_full + WPB - 1) / WPB;
        if (grid > 512) grid = 512;        // persistent, 2 blocks/CU
        spconv_pipe_kernel<<<grid, BLK, 0, stream>>>(pkf, w, nbr, out, n_full);
    }
    if (rem > 0)
        spconv_tail_kernel<<<1, 64, 0, stream>>>(pkf, w, nbr, out, n_pts, n_full * 64);
}